// Round 11
// baseline (631.383 us; speedup 1.0000x reference)
//
#include <hip/hip_runtime.h>
#include <math.h>

#define BB 32
#define NN 4096
#define DD 768
#define HH 384
#define NCH 8   // feat N-chunks per (b, d-block)

typedef _Float16 half8 __attribute__((ext_vector_type(8)));
typedef __fp16 fp16x2 __attribute__((ext_vector_type(2)));
typedef float f32x4 __attribute__((ext_vector_type(4)));

// ---------------- Kernel 0: pre-split w1 into f16 hi/lo MFMA-B fragments ----------------
// frag (cf, kg): lane l holds col c = cf*16 + (l&15), k = kg*32 + (l>>4)*8 + i.
// Layout: frag[(kg*24 + cf)*64 + lane][8 halves].
__global__ __launch_bounds__(64) void fapf_prep_w(
    const float* __restrict__ w1, short* __restrict__ whf, short* __restrict__ wlf)
{
    const int cf = blockIdx.x;        // 0..23
    const int kg = blockIdx.y;        // 0..23
    const int l  = threadIdx.x;       // 0..63
    const int c  = cf * 16 + (l & 15);
    const int kb = kg * 32 + (l >> 4) * 8;

    short hs[8], ls[8];
#pragma unroll
    for (int i = 0; i < 8; i++) {
        float v = w1[(size_t)(kb + i) * HH + c];
        _Float16 hi = (_Float16)v;
        _Float16 lo = (_Float16)(v - (float)hi);
        hs[i] = *(short*)&hi;
        ls[i] = *(short*)&lo;
    }
    size_t base = ((size_t)(kg * 24 + cf) * 64 + l) * 8;
#pragma unroll
    for (int i = 0; i < 8; i++) { whf[base + i] = hs[i]; wlf[base + i] = ls[i]; }
}

// ---------------- Kernel 1: scores via 3-term f16-split MFMA ----------------
// ROUND-14: OCCUPANCY, the one untested axis. Every clean schedule (depth-0/1/2,
// half-b, LDS-only barrier) pinned at 285-306us / ~35% MfmaUtil at 2-2.6
// waves/EU -- VMEM volume, pipeline depth, and barrier semantics all proven
// non-binding (R5/R8/R9/R10 A/Bs). Per-chunk serial path ~930cy MFMA +
// ~500cy unhidden holes => 2 waves/EU caps matrix busy at ~50% ideal, 35%
// real. This round: R5's depth-1 structure (best measured, 285us), whose
// natural allocation was EXACTLY 80 arch + 48 acc = 128 regs = the 4-wave/EU
// budget, + R8's cheaper pkrtz split, at waves_per_eu(4). A valid 128-reg
// allocation exists (R5's own asm) so this should allocate without spill.
// TRIPWIRE: WRITE_SIZE must be 512KB (R4/R7 lesson: over-budget -> scratch).
__global__ __launch_bounds__(256)
__attribute__((amdgpu_waves_per_eu(4)))
void fapf_scores_mfma(
    const float* __restrict__ x, const short* __restrict__ whf,
    const short* __restrict__ wlf, const float* __restrict__ b1,
    const float* __restrict__ w2, const float* __restrict__ b2,
    float* __restrict__ scores)
{
    __shared__ __align__(16) short xh[2][32 * 64];
    __shared__ __align__(16) short xl[2][32 * 64];
    __shared__ float part[32][4];

    const int tid = threadIdx.x;
    const int l   = tid & 63;
    const int cw  = tid >> 6;         // wave = col quarter (96 cols)
    const int t0  = blockIdx.x * 32;  // token base

    f32x4 acc[2][6];
#pragma unroll
    for (int fr = 0; fr < 2; fr++)
#pragma unroll
        for (int cf = 0; cf < 6; cf++) acc[fr][cf] = (f32x4){0.f, 0.f, 0.f, 0.f};

    // per-wave fragment bases: frag (kg, cf') at [(kg*24 + cw*6 + cf)*64 + l]
    const half8* whp = (const half8*)whf + (size_t)(cw * 6) * 64 + l;
    const half8* wlp = (const half8*)wlf + (size_t)(cw * 6) * 64 + l;

    float4 xv[2];

#define LOADX(ch)                                                            \
    {                                                                        \
        _Pragma("unroll")                                                    \
        for (int it = 0; it < 2; it++) {                                     \
            int id = it * 256 + tid;                                         \
            xv[it] = *(const float4*)&x[(size_t)(t0 + (id >> 4)) * DD        \
                                        + (ch) * 64 + (id & 15) * 4];        \
        }                                                                    \
    }

#define SPLITWRITE(buf)                                                      \
    {                                                                        \
        _Pragma("unroll")                                                    \
        for (int it = 0; it < 2; it++) {                                     \
            int id = it * 256 + tid;                                         \
            int row = id >> 4, seg = id & 15;                                \
            float vv[4] = {xv[it].x, xv[it].y, xv[it].z, xv[it].w};          \
            union { fp16x2 h; unsigned int u; } h0, h1, p0, p1;              \
            h0.h = __builtin_amdgcn_cvt_pkrtz(vv[0], vv[1]);                 \
            h1.h = __builtin_amdgcn_cvt_pkrtz(vv[2], vv[3]);                 \
            float l0 = vv[0] - (float)h0.h[0];                               \
            float l1 = vv[1] - (float)h0.h[1];                               \
            float l2 = vv[2] - (float)h1.h[0];                               \
            float l3 = vv[3] - (float)h1.h[1];                               \
            p0.h = __builtin_amdgcn_cvt_pkrtz(l0, l1);                       \
            p1.h = __builtin_amdgcn_cvt_pkrtz(l2, l3);                       \
            uint2 uh, ul;                                                    \
            uh.x = h0.u; uh.y = h1.u;                                        \
            ul.x = p0.u; ul.y = p1.u;                                        \
            int idx = (row * 64 + seg * 4) ^ ((row & 7) << 3);               \
            *(uint2*)&xh[buf][idx] = uh;                                     \
            *(uint2*)&xl[buf][idx] = ul;                                     \
        }                                                                    \
    }

#define LOADB(dst, ptr, kg)                                                  \
    {                                                                        \
        _Pragma("unroll")                                                    \
        for (int cf = 0; cf < 6; cf++)                                       \
            dst[cf] = (ptr)[(size_t)(kg) * 1536 + (size_t)cf * 64];          \
    }

    // prologue: chunk 0 staged, chunk 1 in flight, first bh term in flight
    LOADX(0);
    SPLITWRITE(0);
    half8 bA[6], bB[6];
    LOADB(bA, whp, 0);                 // bh(kg=0)
    __syncthreads();
    LOADX(1);

    for (int c = 0; c < 12; c++) {
        const int cur = c & 1;

#pragma unroll
        for (int ks = 0; ks < 2; ks++) {
            const int kg = c * 2 + ks;

            // a fragments for this kg (LDS)
            half8 ah[2], al[2];
#pragma unroll
            for (int fr = 0; fr < 2; fr++) {
                int row = fr * 16 + (l & 15);
                int idx = (row * 64 + ks * 32 + (l >> 4) * 8) ^ ((row & 7) << 3);
                ah[fr] = *(const half8*)&xh[cur][idx];
                al[fr] = *(const half8*)&xl[cur][idx];
            }

            // issue NEXT term's loads (bl of this kg) before consuming bA=bh(kg)
            LOADB(bB, wlp, kg);

            __builtin_amdgcn_s_setprio(1);
#pragma unroll
            for (int fr = 0; fr < 2; fr++)
#pragma unroll
                for (int cf = 0; cf < 6; cf++)
                    acc[fr][cf] = __builtin_amdgcn_mfma_f32_16x16x32_f16(
                        ah[fr], bA[cf], acc[fr][cf], 0, 0, 0);
#pragma unroll
            for (int fr = 0; fr < 2; fr++)
#pragma unroll
                for (int cf = 0; cf < 6; cf++)
                    acc[fr][cf] = __builtin_amdgcn_mfma_f32_16x16x32_f16(
                        al[fr], bA[cf], acc[fr][cf], 0, 0, 0);
            __builtin_amdgcn_s_setprio(0);

            // issue bh of the NEXT kg before consuming bB=bl(kg)
            if (kg < 23) LOADB(bA, whp, kg + 1);

            __builtin_amdgcn_s_setprio(1);
#pragma unroll
            for (int fr = 0; fr < 2; fr++)
#pragma unroll
                for (int cf = 0; cf < 6; cf++)
                    acc[fr][cf] = __builtin_amdgcn_mfma_f32_16x16x32_f16(
                        ah[fr], bB[cf], acc[fr][cf], 0, 0, 0);
            __builtin_amdgcn_s_setprio(0);
        }

        if (c < 11) {
            SPLITWRITE(cur ^ 1);       // chunk c+1 -> other buffer
            __syncthreads();           // single barrier per chunk
            if (c < 10) LOADX(c + 2);  // flies under next chunk's MFMAs
        }
    }

    // ---- epilogue: +b1, exact GELU, *w2, partial row-sums ----
    float b1v[6], w2v[6];
#pragma unroll
    for (int cf = 0; cf < 6; cf++) {
        int col = cw * 96 + cf * 16 + (l & 15);
        b1v[cf] = b1[col];
        w2v[cf] = w2[col];
    }
    float p[2][4];
#pragma unroll
    for (int fr = 0; fr < 2; fr++)
#pragma unroll
        for (int j = 0; j < 4; j++) p[fr][j] = 0.f;
#pragma unroll
    for (int fr = 0; fr < 2; fr++)
#pragma unroll
        for (int cf = 0; cf < 6; cf++)
#pragma unroll
            for (int j = 0; j < 4; j++) {
                float hh = acc[fr][cf][j] + b1v[cf];
                float g  = 0.5f * hh * (1.f + erff(hh * 0.70710678118654752f));
                p[fr][j] = fmaf(g, w2v[cf], p[fr][j]);
            }
#pragma unroll
    for (int m = 8; m >= 1; m >>= 1)
#pragma unroll
        for (int fr = 0; fr < 2; fr++)
#pragma unroll
            for (int j = 0; j < 4; j++)
                p[fr][j] += __shfl_xor(p[fr][j], m, 64);

    if ((l & 15) == 0) {
#pragma unroll
        for (int fr = 0; fr < 2; fr++)
#pragma unroll
            for (int j = 0; j < 4; j++) {
                int row = fr * 16 + (l >> 4) * 4 + j;
                part[row][cw] = p[fr][j];
            }
    }
    __syncthreads();
    if (tid < 32) {
        float lg = part[tid][0] + part[tid][1] + part[tid][2] + part[tid][3] + b2[0];
        scores[t0 + tid] = 1.f / (1.f + expf(-lg));
    }
#undef LOADX
#undef SPLITWRITE
#undef LOADB
}

// ---------------- Kernel 2: top-k threshold + fused mask/weights + compaction ----------------
__global__ __launch_bounds__(1024) void fapf_select_kernel(
    const float* __restrict__ scores, const int* __restrict__ pct_p,
    float* __restrict__ weights, float* __restrict__ mask,
    float* __restrict__ feat, int* __restrict__ kidx,
    float* __restrict__ kw, int* __restrict__ kcnt)
{
    __shared__ float s[NN];
    __shared__ float red[1024];
    __shared__ int scnt;
    const int b = blockIdx.x, tid = threadIdx.x;

    if (tid == 0) scnt = 0;
    for (int i = tid; i < DD; i += 1024) feat[b * DD + i] = 0.f;
    for (int i = tid; i < NN; i += 1024) s[i] = scores[b * NN + i];
    __syncthreads();

    for (int k = 2; k <= NN; k <<= 1) {
        for (int j = k >> 1; j > 0; j >>= 1) {
            for (int i = tid; i < NN; i += 1024) {
                int ixj = i ^ j;
                if (ixj > i) {
                    bool up = ((i & k) == 0);
                    float a = s[i], c = s[ixj];
                    if (up ? (a > c) : (a < c)) { s[i] = c; s[ixj] = a; }
                }
            }
            __syncthreads();
        }
    }

    int pct = pct_p[0];
    long long kcl = (long long)NN * pct / 100;
    int kc = (int)kcl;
    if (kc < 1) kc = 1;
    if (kc > NN) kc = NN;
    float thr = s[NN - kc];   // k-th largest

    float local = 0.f;
    for (int i = tid; i < NN; i += 1024) {
        float v = scores[b * NN + i];
        if (v >= thr) local += v;
    }
    red[tid] = local;
    __syncthreads();
    for (int step = 512; step > 0; step >>= 1) {
        if (tid < step) red[tid] += red[tid + step];
        __syncthreads();
    }
    float inv = 1.f / (red[0] + 1e-12f);
    const int lane = tid & 63;
    for (int i = tid; i < NN; i += 1024) {
        float v = scores[b * NN + i];
        bool keep = (v >= thr);
        float m = keep ? 1.f : 0.f;
        weights[b * NN + i] = v * m * inv;
        mask[b * NN + i]    = m;
        if (kidx) {
            unsigned long long bal = __ballot(keep);
            int base = 0;
            if (lane == 0) base = atomicAdd(&scnt, __popcll(bal));
            base = __shfl(base, 0, 64);
            if (keep) {
                int off = __popcll(bal & ((1ULL << lane) - 1ULL));
                kidx[b * NN + base + off] = i;
                kw[b * NN + base + off]   = v * inv;
            }
        }
    }
    if (kidx) {
        __syncthreads();
        if (tid == 0) kcnt[b] = scnt;
    }
}

// ---------------- Kernel 3a: filtered_feat from compact list ----------------
__global__ __launch_bounds__(256) void fapf_feat_compact(
    const float* __restrict__ x, const int* __restrict__ kidx,
    const float* __restrict__ kw, const int* __restrict__ kcnt,
    float* __restrict__ feat)
{
    const int b  = blockIdx.y;
    const int d0 = blockIdx.x * 64;
    const int ch = blockIdx.z;
    const int dl = threadIdx.x & 63;
    const int ng = threadIdx.x >> 6;   // 0..3 (wave id)

    const int cnt = kcnt[b];
    int per = (cnt + NCH - 1) / NCH;
    int j0 = ch * per; if (j0 > cnt) j0 = cnt;
    int j1 = j0 + per; if (j1 > cnt) j1 = cnt;
    int len = j1 - j0;
    int per_w = (len + 3) >> 2;
    int s = j0 + ng * per_w;
    int e = s + per_w; if (e > j1) e = j1;

    const float* xb  = x + (size_t)b * NN * DD + d0 + dl;
    const int*   ib  = kidx + b * NN;
    const float* wbp = kw + b * NN;

    float a[8];
#pragma unroll
    for (int u = 0; u < 8; u++) a[u] = 0.f;

    int j = s;
    for (; j + 8 <= e; j += 8) {
        int   idx[8];
        float ww[8];
#pragma unroll
        for (int u = 0; u < 8; u++) { idx[u] = ib[j + u]; ww[u] = wbp[j + u]; }
#pragma unroll
        for (int u = 0; u < 8; u++)
            a[u] = fmaf(ww[u], xb[(size_t)idx[u] * DD], a[u]);
    }
    for (; j < e; j++)
        a[0] = fmaf(wbp[j], xb[(size_t)ib[j] * DD], a[0]);

    float acc = ((a[0] + a[1]) + (a[2] + a[3])) + ((a[4] + a[5]) + (a[6] + a[7]));

    __shared__ float red[4][64];
    red[ng][dl] = acc;
    __syncthreads();
    if (threadIdx.x < 64) {
        float v = (red[0][dl] + red[1][dl]) + (red[2][dl] + red[3][dl]);
        atomicAdd(&feat[b * DD + d0 + dl], v);
    }
}

// ---------------- Kernel 3b: dense fallback ----------------
__global__ __launch_bounds__(256) void fapf_feat_dense(
    const float* __restrict__ x, const float* __restrict__ weights,
    float* __restrict__ feat)
{
    const int b  = blockIdx.y;
    const int d0 = blockIdx.x * 64;
    const int dl = threadIdx.x & 63;
    const int ng = threadIdx.x >> 6;   // 0..3

    const float* xb = x + (size_t)b * NN * DD;
    const float* wb = weights + b * NN;

    float a0 = 0.f, a1 = 0.f, a2 = 0.f, a3 = 0.f;
    for (int n = ng; n < NN; n += 16) {
        float w0 = wb[n], w1v = wb[n + 4], w2v = wb[n + 8], w3 = wb[n + 12];
        float v0 = xb[(size_t)(n)      * DD + d0 + dl];
        float v1 = xb[(size_t)(n + 4)  * DD + d0 + dl];
        float v2 = xb[(size_t)(n + 8)  * DD + d0 + dl];
        float v3 = xb[(size_t)(n + 12) * DD + d0 + dl];
        a0 = fmaf(w0, v0, a0);
        a1 = fmaf(w1v, v1, a1);
        a2 = fmaf(w2v, v2, a2);
        a3 = fmaf(w3, v3, a3);
    }
    float acc = (a0 + a1) + (a2 + a3);

    __shared__ float red[4][64];
    red[ng][dl] = acc;
    __syncthreads();
    if (threadIdx.x < 64) {
        feat[b * DD + d0 + dl] =
            (red[0][dl] + red[1][dl]) + (red[2][dl] + red[3][dl]);
    }
}

extern "C" void kernel_launch(void* const* d_in, const int* in_sizes, int n_in,
                              void* d_out, int out_size, void* d_ws, size_t ws_size,
                              hipStream_t stream) {
    const float* x   = (const float*)d_in[0];
    const float* w1  = (const float*)d_in[1];
    const float* b1  = (const float*)d_in[2];
    const float* w2  = (const float*)d_in[3];
    const float* b2  = (const float*)d_in[4];
    const int*   pct = (const int*)d_in[5];

    float* out = (float*)d_out;
    float* feat    = out;                         // [32,768]
    float* weights = out + BB * DD;               // [32,4096]
    float* scores  = weights + BB * NN;           // [32,4096]
    float* mask    = scores + BB * NN;            // [32,4096]

    // d_ws layout: whf (576KB) | wlf (576KB) | kidx (512KB) | kw (512KB) | kcnt (128B)
    short* whf  = (short*)d_ws;
    short* wlf  = whf + 24 * 24 * 64 * 8;
    int*   kidx = (int*)(wlf + 24 * 24 * 64 * 8);
    float* kw   = (float*)(kidx + BB * NN);
    int*   kcnt = (int*)(kw + BB * NN);

    const size_t needed = 2 * (size_t)(24 * 24 * 64 * 8) * sizeof(short)
                        + (size_t)BB * NN * (sizeof(int) + sizeof(float))
                        + BB * sizeof(int);
    const bool compact = ws_size >= needed;

    fapf_prep_w<<<dim3(24, 24), dim3(64), 0, stream>>>(w1, whf, wlf);
    fapf_scores_mfma<<<dim3(BB * NN / 32), dim3(256), 0, stream>>>(
        x, whf, wlf, b1, w2, b2, scores);
    fapf_select_kernel<<<dim3(BB), dim3(1024), 0, stream>>>(
        scores, pct, weights, mask, feat,
        compact ? kidx : (int*)nullptr, kw, kcnt);
    if (compact) {
        fapf_feat_compact<<<dim3(DD / 64, BB, NCH), dim3(256), 0, stream>>>(
            x, kidx, kw, kcnt, feat);
    } else {
        fapf_feat_dense<<<dim3(DD / 64, BB), dim3(256), 0, stream>>>(
            x, weights, feat);
    }
}

// Round 12
// 359.547 us; speedup vs baseline: 1.7561x; 1.7561x over previous
//
#include <hip/hip_runtime.h>
#include <math.h>

#define BB 32
#define NN 4096
#define DD 768
#define HH 384
#define NCH 8   // feat N-chunks per (b, d-block)

typedef _Float16 half8 __attribute__((ext_vector_type(8)));
typedef float f32x4 __attribute__((ext_vector_type(4)));

// ---------------- Kernel 0: pre-split w1 into f16 hi/lo MFMA-B fragments ----------------
// frag (cf, kg): lane l holds col c = cf*16 + (l&15), k = kg*32 + (l>>4)*8 + i.
// Layout: frag[(kg*24 + cf)*64 + lane][8 halves].
__global__ __launch_bounds__(64) void fapf_prep_w(
    const float* __restrict__ w1, short* __restrict__ whf, short* __restrict__ wlf)
{
    const int cf = blockIdx.x;        // 0..23
    const int kg = blockIdx.y;        // 0..23
    const int l  = threadIdx.x;       // 0..63
    const int c  = cf * 16 + (l & 15);
    const int kb = kg * 32 + (l >> 4) * 8;

    short hs[8], ls[8];
#pragma unroll
    for (int i = 0; i < 8; i++) {
        float v = w1[(size_t)(kb + i) * HH + c];
        _Float16 hi = (_Float16)v;
        _Float16 lo = (_Float16)(v - (float)hi);
        hs[i] = *(short*)&hi;
        ls[i] = *(short*)&lo;
    }
    size_t base = ((size_t)(kg * 24 + cf) * 64 + l) * 8;
#pragma unroll
    for (int i = 0; i < 8; i++) { whf[base + i] = hs[i]; wlf[base + i] = ls[i]; }
}

// ---------------- Kernel 1: scores via 3-term f16-split MFMA ----------------
// R5-EXACT base (best clean config: 285us, depth-1 b-pipeline, waves_per_eu(3),
// VGPR 80, WRITE 512KB) with ONE change -- ROUND-15 vmcnt-FIFO convoy fix:
// vmcnt retires IN ISSUE ORDER, so the old structure (LOADX issued at the
// chunk boundary, BEFORE the next chunk's b-loads) made every first b-consume
// of a chunk wait for the ~600-900cy HBM x-load to retire (wait for b =
// vmcnt<=#younger => all older ops incl. x must retire). One ~300-500cy stall
// per chunk per wave, invariant under b-depth/b-volume/barrier-type -- which
// is exactly what R5/R8/R9/R10 measured (all pinned ~35% MfmaUtil). Fix:
// issue LOADX(c+1) INSIDE the chunk, AFTER the term's b-loads (b-waits then
// never force x; the first loads younger than x are consumed a full term
// ~1700cy later; x itself has ~a chunk before SPLITWRITE). xv now lives only
// within one chunk (less register pressure). TRIPWIRE: WRITE_SIZE == 512KB.
__global__ __launch_bounds__(256)
__attribute__((amdgpu_waves_per_eu(3)))
void fapf_scores_mfma(
    const float* __restrict__ x, const short* __restrict__ whf,
    const short* __restrict__ wlf, const float* __restrict__ b1,
    const float* __restrict__ w2, const float* __restrict__ b2,
    float* __restrict__ scores)
{
    __shared__ __align__(16) short xh[2][32 * 64];
    __shared__ __align__(16) short xl[2][32 * 64];
    __shared__ float part[32][4];

    const int tid = threadIdx.x;
    const int l   = tid & 63;
    const int cw  = tid >> 6;         // wave = col quarter (96 cols)
    const int t0  = blockIdx.x * 32;  // token base

    f32x4 acc[2][6];
#pragma unroll
    for (int fr = 0; fr < 2; fr++)
#pragma unroll
        for (int cf = 0; cf < 6; cf++) acc[fr][cf] = (f32x4){0.f, 0.f, 0.f, 0.f};

    // per-wave fragment bases: frag (kg, cf') at [(kg*24 + cw*6 + cf)*64 + l]
    const half8* whp = (const half8*)whf + (size_t)(cw * 6) * 64 + l;
    const half8* wlp = (const half8*)wlf + (size_t)(cw * 6) * 64 + l;

    float4 xv[2];

#define LOADX(ch)                                                            \
    {                                                                        \
        _Pragma("unroll")                                                    \
        for (int it = 0; it < 2; it++) {                                     \
            int id = it * 256 + tid;                                         \
            xv[it] = *(const float4*)&x[(size_t)(t0 + (id >> 4)) * DD        \
                                        + (ch) * 64 + (id & 15) * 4];        \
        }                                                                    \
    }

#define SPLITWRITE(buf)                                                      \
    {                                                                        \
        _Pragma("unroll")                                                    \
        for (int it = 0; it < 2; it++) {                                     \
            int id = it * 256 + tid;                                         \
            int row = id >> 4, seg = id & 15;                                \
            union { short s[4]; uint2 u; } ph, pl;                           \
            float vv[4] = {xv[it].x, xv[it].y, xv[it].z, xv[it].w};          \
            _Pragma("unroll")                                                \
            for (int i = 0; i < 4; i++) {                                    \
                _Float16 hi = (_Float16)vv[i];                               \
                _Float16 lo = (_Float16)(vv[i] - (float)hi);                 \
                ph.s[i] = *(short*)&hi;                                      \
                pl.s[i] = *(short*)&lo;                                      \
            }                                                                \
            int idx = (row * 64 + seg * 4) ^ ((row & 7) << 3);               \
            *(uint2*)&xh[buf][idx] = ph.u;                                   \
            *(uint2*)&xl[buf][idx] = pl.u;                                   \
        }                                                                    \
    }

#define LOADB(dst, ptr, kg)                                                  \
    {                                                                        \
        _Pragma("unroll")                                                    \
        for (int cf = 0; cf < 6; cf++)                                       \
            dst[cf] = (ptr)[(size_t)(kg) * 1536 + (size_t)cf * 64];          \
    }

    // prologue: chunk 0 staged, first bh term in flight.
    // NOTE: no boundary LOADX -- x for chunk c+1 is issued INSIDE chunk c.
    LOADX(0);
    SPLITWRITE(0);
    half8 bA[6], bB[6];
    LOADB(bA, whp, 0);                 // bh(kg=0)
    __syncthreads();

    for (int c = 0; c < 12; c++) {
        const int cur = c & 1;

#pragma unroll
        for (int ks = 0; ks < 2; ks++) {
            const int kg = c * 2 + ks;

            // a fragments for this kg (LDS)
            half8 ah[2], al[2];
#pragma unroll
            for (int fr = 0; fr < 2; fr++) {
                int row = fr * 16 + (l & 15);
                int idx = (row * 64 + ks * 32 + (l >> 4) * 8) ^ ((row & 7) << 3);
                ah[fr] = *(const half8*)&xh[cur][idx];
                al[fr] = *(const half8*)&xl[cur][idx];
            }

            // issue NEXT term's loads (bl of this kg) before consuming bA=bh(kg)
            LOADB(bB, wlp, kg);

            __builtin_amdgcn_s_setprio(1);
#pragma unroll
            for (int fr = 0; fr < 2; fr++)
#pragma unroll
                for (int cf = 0; cf < 6; cf++)
                    acc[fr][cf] = __builtin_amdgcn_mfma_f32_16x16x32_f16(
                        ah[fr], bA[cf], acc[fr][cf], 0, 0, 0);
#pragma unroll
            for (int fr = 0; fr < 2; fr++)
#pragma unroll
                for (int cf = 0; cf < 6; cf++)
                    acc[fr][cf] = __builtin_amdgcn_mfma_f32_16x16x32_f16(
                        al[fr], bA[cf], acc[fr][cf], 0, 0, 0);
            __builtin_amdgcn_s_setprio(0);

            // issue bh of the NEXT kg before consuming bB=bl(kg)
            if (kg < 23) LOADB(bA, whp, kg + 1);

            // CONVOY FIX: x-prefetch for chunk c+1 issued here -- AFTER this
            // term's b-loads (so no b-wait in this term forces x) and a full
            // term before the next b-loads' consumes (~1700cy > HBM latency).
            if (ks == 0 && c < 11) LOADX(c + 1);

            __builtin_amdgcn_s_setprio(1);
#pragma unroll
            for (int fr = 0; fr < 2; fr++)
#pragma unroll
                for (int cf = 0; cf < 6; cf++)
                    acc[fr][cf] = __builtin_amdgcn_mfma_f32_16x16x32_f16(
                        ah[fr], bB[cf], acc[fr][cf], 0, 0, 0);
            __builtin_amdgcn_s_setprio(0);
        }

        if (c < 11) {
            SPLITWRITE(cur ^ 1);       // chunk c+1 -> other buffer (xv from this chunk)
            __syncthreads();           // single barrier per chunk
        }
    }

    // ---- epilogue: +b1, exact GELU, *w2, partial row-sums ----
    float b1v[6], w2v[6];
#pragma unroll
    for (int cf = 0; cf < 6; cf++) {
        int col = cw * 96 + cf * 16 + (l & 15);
        b1v[cf] = b1[col];
        w2v[cf] = w2[col];
    }
    float p[2][4];
#pragma unroll
    for (int fr = 0; fr < 2; fr++)
#pragma unroll
        for (int j = 0; j < 4; j++) p[fr][j] = 0.f;
#pragma unroll
    for (int fr = 0; fr < 2; fr++)
#pragma unroll
        for (int cf = 0; cf < 6; cf++)
#pragma unroll
            for (int j = 0; j < 4; j++) {
                float hh = acc[fr][cf][j] + b1v[cf];
                float g  = 0.5f * hh * (1.f + erff(hh * 0.70710678118654752f));
                p[fr][j] = fmaf(g, w2v[cf], p[fr][j]);
            }
#pragma unroll
    for (int m = 8; m >= 1; m >>= 1)
#pragma unroll
        for (int fr = 0; fr < 2; fr++)
#pragma unroll
            for (int j = 0; j < 4; j++)
                p[fr][j] += __shfl_xor(p[fr][j], m, 64);

    if ((l & 15) == 0) {
#pragma unroll
        for (int fr = 0; fr < 2; fr++)
#pragma unroll
            for (int j = 0; j < 4; j++) {
                int row = fr * 16 + (l >> 4) * 4 + j;
                part[row][cw] = p[fr][j];
            }
    }
    __syncthreads();
    if (tid < 32) {
        float lg = part[tid][0] + part[tid][1] + part[tid][2] + part[tid][3] + b2[0];
        scores[t0 + tid] = 1.f / (1.f + expf(-lg));
    }
#undef LOADX
#undef SPLITWRITE
#undef LOADB
}

// ---------------- Kernel 2: top-k threshold + fused mask/weights + compaction ----------------
__global__ __launch_bounds__(1024) void fapf_select_kernel(
    const float* __restrict__ scores, const int* __restrict__ pct_p,
    float* __restrict__ weights, float* __restrict__ mask,
    float* __restrict__ feat, int* __restrict__ kidx,
    float* __restrict__ kw, int* __restrict__ kcnt)
{
    __shared__ float s[NN];
    __shared__ float red[1024];
    __shared__ int scnt;
    const int b = blockIdx.x, tid = threadIdx.x;

    if (tid == 0) scnt = 0;
    for (int i = tid; i < DD; i += 1024) feat[b * DD + i] = 0.f;
    for (int i = tid; i < NN; i += 1024) s[i] = scores[b * NN + i];
    __syncthreads();

    for (int k = 2; k <= NN; k <<= 1) {
        for (int j = k >> 1; j > 0; j >>= 1) {
            for (int i = tid; i < NN; i += 1024) {
                int ixj = i ^ j;
                if (ixj > i) {
                    bool up = ((i & k) == 0);
                    float a = s[i], c = s[ixj];
                    if (up ? (a > c) : (a < c)) { s[i] = c; s[ixj] = a; }
                }
            }
            __syncthreads();
        }
    }

    int pct = pct_p[0];
    long long kcl = (long long)NN * pct / 100;
    int kc = (int)kcl;
    if (kc < 1) kc = 1;
    if (kc > NN) kc = NN;
    float thr = s[NN - kc];   // k-th largest

    float local = 0.f;
    for (int i = tid; i < NN; i += 1024) {
        float v = scores[b * NN + i];
        if (v >= thr) local += v;
    }
    red[tid] = local;
    __syncthreads();
    for (int step = 512; step > 0; step >>= 1) {
        if (tid < step) red[tid] += red[tid + step];
        __syncthreads();
    }
    float inv = 1.f / (red[0] + 1e-12f);
    const int lane = tid & 63;
    for (int i = tid; i < NN; i += 1024) {
        float v = scores[b * NN + i];
        bool keep = (v >= thr);
        float m = keep ? 1.f : 0.f;
        weights[b * NN + i] = v * m * inv;
        mask[b * NN + i]    = m;
        if (kidx) {
            unsigned long long bal = __ballot(keep);
            int base = 0;
            if (lane == 0) base = atomicAdd(&scnt, __popcll(bal));
            base = __shfl(base, 0, 64);
            if (keep) {
                int off = __popcll(bal & ((1ULL << lane) - 1ULL));
                kidx[b * NN + base + off] = i;
                kw[b * NN + base + off]   = v * inv;
            }
        }
    }
    if (kidx) {
        __syncthreads();
        if (tid == 0) kcnt[b] = scnt;
    }
}

// ---------------- Kernel 3a: filtered_feat from compact list ----------------
__global__ __launch_bounds__(256) void fapf_feat_compact(
    const float* __restrict__ x, const int* __restrict__ kidx,
    const float* __restrict__ kw, const int* __restrict__ kcnt,
    float* __restrict__ feat)
{
    const int b  = blockIdx.y;
    const int d0 = blockIdx.x * 64;
    const int ch = blockIdx.z;
    const int dl = threadIdx.x & 63;
    const int ng = threadIdx.x >> 6;   // 0..3 (wave id)

    const int cnt = kcnt[b];
    int per = (cnt + NCH - 1) / NCH;
    int j0 = ch * per; if (j0 > cnt) j0 = cnt;
    int j1 = j0 + per; if (j1 > cnt) j1 = cnt;
    int len = j1 - j0;
    int per_w = (len + 3) >> 2;
    int s = j0 + ng * per_w;
    int e = s + per_w; if (e > j1) e = j1;

    const float* xb  = x + (size_t)b * NN * DD + d0 + dl;
    const int*   ib  = kidx + b * NN;
    const float* wbp = kw + b * NN;

    float a[8];
#pragma unroll
    for (int u = 0; u < 8; u++) a[u] = 0.f;

    int j = s;
    for (; j + 8 <= e; j += 8) {
        int   idx[8];
        float ww[8];
#pragma unroll
        for (int u = 0; u < 8; u++) { idx[u] = ib[j + u]; ww[u] = wbp[j + u]; }
#pragma unroll
        for (int u = 0; u < 8; u++)
            a[u] = fmaf(ww[u], xb[(size_t)idx[u] * DD], a[u]);
    }
    for (; j < e; j++)
        a[0] = fmaf(wbp[j], xb[(size_t)ib[j] * DD], a[0]);

    float acc = ((a[0] + a[1]) + (a[2] + a[3])) + ((a[4] + a[5]) + (a[6] + a[7]));

    __shared__ float red[4][64];
    red[ng][dl] = acc;
    __syncthreads();
    if (threadIdx.x < 64) {
        float v = (red[0][dl] + red[1][dl]) + (red[2][dl] + red[3][dl]);
        atomicAdd(&feat[b * DD + d0 + dl], v);
    }
}

// ---------------- Kernel 3b: dense fallback ----------------
__global__ __launch_bounds__(256) void fapf_feat_dense(
    const float* __restrict__ x, const float* __restrict__ weights,
    float* __restrict__ feat)
{
    const int b  = blockIdx.y;
    const int d0 = blockIdx.x * 64;
    const int dl = threadIdx.x & 63;
    const int ng = threadIdx.x >> 6;   // 0..3

    const float* xb = x + (size_t)b * NN * DD;
    const float* wb = weights + b * NN;

    float a0 = 0.f, a1 = 0.f, a2 = 0.f, a3 = 0.f;
    for (int n = ng; n < NN; n += 16) {
        float w0 = wb[n], w1v = wb[n + 4], w2v = wb[n + 8], w3 = wb[n + 12];
        float v0 = xb[(size_t)(n)      * DD + d0 + dl];
        float v1 = xb[(size_t)(n + 4)  * DD + d0 + dl];
        float v2 = xb[(size_t)(n + 8)  * DD + d0 + dl];
        float v3 = xb[(size_t)(n + 12) * DD + d0 + dl];
        a0 = fmaf(w0, v0, a0);
        a1 = fmaf(w1v, v1, a1);
        a2 = fmaf(w2v, v2, a2);
        a3 = fmaf(w3, v3, a3);
    }
    float acc = (a0 + a1) + (a2 + a3);

    __shared__ float red[4][64];
    red[ng][dl] = acc;
    __syncthreads();
    if (threadIdx.x < 64) {
        feat[b * DD + d0 + dl] =
            (red[0][dl] + red[1][dl]) + (red[2][dl] + red[3][dl]);
    }
}

extern "C" void kernel_launch(void* const* d_in, const int* in_sizes, int n_in,
                              void* d_out, int out_size, void* d_ws, size_t ws_size,
                              hipStream_t stream) {
    const float* x   = (const float*)d_in[0];
    const float* w1  = (const float*)d_in[1];
    const float* b1  = (const float*)d_in[2];
    const float* w2  = (const float*)d_in[3];
    const float* b2  = (const float*)d_in[4];
    const int*   pct = (const int*)d_in[5];

    float* out = (float*)d_out;
    float* feat    = out;                         // [32,768]
    float* weights = out + BB * DD;               // [32,4096]
    float* scores  = weights + BB * NN;           // [32,4096]
    float* mask    = scores + BB * NN;            // [32,4096]

    // d_ws layout: whf (576KB) | wlf (576KB) | kidx (512KB) | kw (512KB) | kcnt (128B)
    short* whf  = (short*)d_ws;
    short* wlf  = whf + 24 * 24 * 64 * 8;
    int*   kidx = (int*)(wlf + 24 * 24 * 64 * 8);
    float* kw   = (float*)(kidx + BB * NN);
    int*   kcnt = (int*)(kw + BB * NN);

    const size_t needed = 2 * (size_t)(24 * 24 * 64 * 8) * sizeof(short)
                        + (size_t)BB * NN * (sizeof(int) + sizeof(float))
                        + BB * sizeof(int);
    const bool compact = ws_size >= needed;

    fapf_prep_w<<<dim3(24, 24), dim3(64), 0, stream>>>(w1, whf, wlf);
    fapf_scores_mfma<<<dim3(BB * NN / 32), dim3(256), 0, stream>>>(
        x, whf, wlf, b1, w2, b2, scores);
    fapf_select_kernel<<<dim3(BB), dim3(1024), 0, stream>>>(
        scores, pct, weights, mask, feat,
        compact ? kidx : (int*)nullptr, kw, kcnt);
    if (compact) {
        fapf_feat_compact<<<dim3(DD / 64, BB, NCH), dim3(256), 0, stream>>>(
            x, kidx, kw, kcnt, feat);
    } else {
        fapf_feat_dense<<<dim3(DD / 64, BB), dim3(256), 0, stream>>>(
            x, weights, feat);
    }
}

// Round 13
// 306.621 us; speedup vs baseline: 2.0592x; 1.1726x over previous
//
#include <hip/hip_runtime.h>
#include <math.h>

#define BB 32
#define NN 4096
#define DD 768
#define HH 384
#define NCH 8   // feat N-chunks per (b, d-block)

typedef _Float16 half8 __attribute__((ext_vector_type(8)));
typedef float f32x4 __attribute__((ext_vector_type(4)));

// ---------------- Kernel 0: pre-split w1 into f16 hi/lo MFMA-B fragments ----------------
__global__ __launch_bounds__(64) void fapf_prep_w(
    const float* __restrict__ w1, short* __restrict__ whf, short* __restrict__ wlf)
{
    const int cf = blockIdx.x;        // 0..23
    const int kg = blockIdx.y;        // 0..23
    const int l  = threadIdx.x;       // 0..63
    const int c  = cf * 16 + (l & 15);
    const int kb = kg * 32 + (l >> 4) * 8;

    short hs[8], ls[8];
#pragma unroll
    for (int i = 0; i < 8; i++) {
        float v = w1[(size_t)(kb + i) * HH + c];
        _Float16 hi = (_Float16)v;
        _Float16 lo = (_Float16)(v - (float)hi);
        hs[i] = *(short*)&hi;
        ls[i] = *(short*)&lo;
    }
    size_t base = ((size_t)(kg * 24 + cf) * 64 + l) * 8;
#pragma unroll
    for (int i = 0; i < 8; i++) { whf[base + i] = hs[i]; wlf[base + i] = ls[i]; }
}

// ---------------- Kernel 1: scores via 3-term f16-split MFMA ----------------
// FROZEN (R12). Six schedule variants (b-depth 0/1/2, half-b, in-body x-issue,
// LDS-only barrier, occupancy 2-4w) all pin at 285-306us = the 2-barrier-loop
// structural ceiling (~41% of the f16 MFMA floor; cf. guide m97 ~36-38%).
__global__ __launch_bounds__(256)
__attribute__((amdgpu_waves_per_eu(3)))
void fapf_scores_mfma(
    const float* __restrict__ x, const short* __restrict__ whf,
    const short* __restrict__ wlf, const float* __restrict__ b1,
    const float* __restrict__ w2, const float* __restrict__ b2,
    float* __restrict__ scores)
{
    __shared__ __align__(16) short xh[2][32 * 64];
    __shared__ __align__(16) short xl[2][32 * 64];
    __shared__ float part[32][4];

    const int tid = threadIdx.x;
    const int l   = tid & 63;
    const int cw  = tid >> 6;         // wave = col quarter (96 cols)
    const int t0  = blockIdx.x * 32;  // token base

    f32x4 acc[2][6];
#pragma unroll
    for (int fr = 0; fr < 2; fr++)
#pragma unroll
        for (int cf = 0; cf < 6; cf++) acc[fr][cf] = (f32x4){0.f, 0.f, 0.f, 0.f};

    const half8* whp = (const half8*)whf + (size_t)(cw * 6) * 64 + l;
    const half8* wlp = (const half8*)wlf + (size_t)(cw * 6) * 64 + l;

    float4 xv[2];

#define LOADX(ch)                                                            \
    {                                                                        \
        _Pragma("unroll")                                                    \
        for (int it = 0; it < 2; it++) {                                     \
            int id = it * 256 + tid;                                         \
            xv[it] = *(const float4*)&x[(size_t)(t0 + (id >> 4)) * DD        \
                                        + (ch) * 64 + (id & 15) * 4];        \
        }                                                                    \
    }

#define SPLITWRITE(buf)                                                      \
    {                                                                        \
        _Pragma("unroll")                                                    \
        for (int it = 0; it < 2; it++) {                                     \
            int id = it * 256 + tid;                                         \
            int row = id >> 4, seg = id & 15;                                \
            union { short s[4]; uint2 u; } ph, pl;                           \
            float vv[4] = {xv[it].x, xv[it].y, xv[it].z, xv[it].w};          \
            _Pragma("unroll")                                                \
            for (int i = 0; i < 4; i++) {                                    \
                _Float16 hi = (_Float16)vv[i];                               \
                _Float16 lo = (_Float16)(vv[i] - (float)hi);                 \
                ph.s[i] = *(short*)&hi;                                      \
                pl.s[i] = *(short*)&lo;                                      \
            }                                                                \
            int idx = (row * 64 + seg * 4) ^ ((row & 7) << 3);               \
            *(uint2*)&xh[buf][idx] = ph.u;                                   \
            *(uint2*)&xl[buf][idx] = pl.u;                                   \
        }                                                                    \
    }

#define LOADB(dst, ptr, kg)                                                  \
    {                                                                        \
        _Pragma("unroll")                                                    \
        for (int cf = 0; cf < 6; cf++)                                       \
            dst[cf] = (ptr)[(size_t)(kg) * 1536 + (size_t)cf * 64];          \
    }

    LOADX(0);
    SPLITWRITE(0);
    half8 bA[6], bB[6];
    LOADB(bA, whp, 0);                 // bh(kg=0)
    __syncthreads();

    for (int c = 0; c < 12; c++) {
        const int cur = c & 1;

#pragma unroll
        for (int ks = 0; ks < 2; ks++) {
            const int kg = c * 2 + ks;

            half8 ah[2], al[2];
#pragma unroll
            for (int fr = 0; fr < 2; fr++) {
                int row = fr * 16 + (l & 15);
                int idx = (row * 64 + ks * 32 + (l >> 4) * 8) ^ ((row & 7) << 3);
                ah[fr] = *(const half8*)&xh[cur][idx];
                al[fr] = *(const half8*)&xl[cur][idx];
            }

            LOADB(bB, wlp, kg);

            __builtin_amdgcn_s_setprio(1);
#pragma unroll
            for (int fr = 0; fr < 2; fr++)
#pragma unroll
                for (int cf = 0; cf < 6; cf++)
                    acc[fr][cf] = __builtin_amdgcn_mfma_f32_16x16x32_f16(
                        ah[fr], bA[cf], acc[fr][cf], 0, 0, 0);
#pragma unroll
            for (int fr = 0; fr < 2; fr++)
#pragma unroll
                for (int cf = 0; cf < 6; cf++)
                    acc[fr][cf] = __builtin_amdgcn_mfma_f32_16x16x32_f16(
                        al[fr], bA[cf], acc[fr][cf], 0, 0, 0);
            __builtin_amdgcn_s_setprio(0);

            if (kg < 23) LOADB(bA, whp, kg + 1);
            if (ks == 0 && c < 11) LOADX(c + 1);

            __builtin_amdgcn_s_setprio(1);
#pragma unroll
            for (int fr = 0; fr < 2; fr++)
#pragma unroll
                for (int cf = 0; cf < 6; cf++)
                    acc[fr][cf] = __builtin_amdgcn_mfma_f32_16x16x32_f16(
                        ah[fr], bB[cf], acc[fr][cf], 0, 0, 0);
            __builtin_amdgcn_s_setprio(0);
        }

        if (c < 11) {
            SPLITWRITE(cur ^ 1);
            __syncthreads();
        }
    }

    // ---- epilogue: +b1, exact GELU, *w2, partial row-sums ----
    float b1v[6], w2v[6];
#pragma unroll
    for (int cf = 0; cf < 6; cf++) {
        int col = cw * 96 + cf * 16 + (l & 15);
        b1v[cf] = b1[col];
        w2v[cf] = w2[col];
    }
    float p[2][4];
#pragma unroll
    for (int fr = 0; fr < 2; fr++)
#pragma unroll
        for (int j = 0; j < 4; j++) p[fr][j] = 0.f;
#pragma unroll
    for (int fr = 0; fr < 2; fr++)
#pragma unroll
        for (int cf = 0; cf < 6; cf++)
#pragma unroll
            for (int j = 0; j < 4; j++) {
                float hh = acc[fr][cf][j] + b1v[cf];
                float g  = 0.5f * hh * (1.f + erff(hh * 0.70710678118654752f));
                p[fr][j] = fmaf(g, w2v[cf], p[fr][j]);
            }
#pragma unroll
    for (int m = 8; m >= 1; m >>= 1)
#pragma unroll
        for (int fr = 0; fr < 2; fr++)
#pragma unroll
            for (int j = 0; j < 4; j++)
                p[fr][j] += __shfl_xor(p[fr][j], m, 64);

    if ((l & 15) == 0) {
#pragma unroll
        for (int fr = 0; fr < 2; fr++)
#pragma unroll
            for (int j = 0; j < 4; j++) {
                int row = fr * 16 + (l >> 4) * 4 + j;
                part[row][cw] = p[fr][j];
            }
    }
    __syncthreads();
    if (tid < 32) {
        float lg = part[tid][0] + part[tid][1] + part[tid][2] + part[tid][3] + b2[0];
        scores[t0 + tid] = 1.f / (1.f + expf(-lg));
    }
#undef LOADX
#undef SPLITWRITE
#undef LOADB
}

// ---------------- Kernel 2: radix-select threshold + fused mask/weights + compaction ----------------
// ROUND-16: bitonic sort (78 barrier passes for one number) -> 4-pass 8-bit
// radix-select on the float bit pattern (positive floats: uint order == float
// order). Per pass: LDS histogram + single-wave shfl suffix-scan = 3 barriers
// (12 total). thr is bit-exact the kc-th largest element (boundary bin is
// non-empty) -> identical `v >= thr` semantics to the sorted version.
__global__ __launch_bounds__(1024) void fapf_select_kernel(
    const float* __restrict__ scores, const int* __restrict__ pct_p,
    float* __restrict__ weights, float* __restrict__ mask,
    float* __restrict__ feat, int* __restrict__ kidx,
    float* __restrict__ kw, int* __restrict__ kcnt)
{
    __shared__ float s[NN];
    __shared__ unsigned int hist[256];
    __shared__ unsigned int sh_bin, sh_above;
    __shared__ float wsum[16];
    __shared__ int scnt;
    const int b = blockIdx.x, tid = threadIdx.x;

    if (tid == 0) scnt = 0;
    for (int i = tid; i < DD; i += 1024) feat[b * DD + i] = 0.f;
    for (int i = tid; i < NN; i += 1024) s[i] = scores[b * NN + i];

    int pct = pct_p[0];
    long long kcl = (long long)NN * pct / 100;
    int kc = (int)kcl;
    if (kc < 1) kc = 1;
    if (kc > NN) kc = NN;

    __syncthreads();

    // ---- 4-pass radix select: find the kc-th largest bit pattern ----
    unsigned int prefix = 0;
    unsigned int kk = (unsigned int)kc;
#pragma unroll
    for (int pass = 0; pass < 4; pass++) {
        const int shift = 24 - pass * 8;
        if (tid < 256) hist[tid] = 0;
        __syncthreads();
        const unsigned int maskAbove =
            (pass == 0) ? 0u : (0xFFFFFFFFu << (shift + 8));
        for (int i = tid; i < NN; i += 1024) {
            unsigned int u = __float_as_uint(s[i]);
            if ((u & maskAbove) == prefix)
                atomicAdd(&hist[(u >> shift) & 0xFFu], 1u);
        }
        __syncthreads();
        if (tid < 64) {
            const int ln = tid;
            unsigned int h0 = hist[4 * ln + 0], h1 = hist[4 * ln + 1];
            unsigned int h2 = hist[4 * ln + 2], h3 = hist[4 * ln + 3];
            unsigned int lsum = h0 + h1 + h2 + h3;
            unsigned int incl = lsum;      // inclusive suffix sum over lanes
#pragma unroll
            for (int off = 1; off < 64; off <<= 1) {
                unsigned int t = __shfl_down(incl, off, 64);
                if (ln + off < 64) incl += t;
            }
            unsigned int above_lanes = incl - lsum;   // lanes > ln
            unsigned int c3 = above_lanes + h3;
            unsigned int c2 = c3 + h2;
            unsigned int c1 = c2 + h1;
            unsigned int c0 = c1 + h0;
            // boundary bin: cum >= kk && next < kk (exactly one across block)
            if (c3 >= kk && above_lanes < kk) { sh_bin = 4u * ln + 3u; sh_above = above_lanes; }
            if (c2 >= kk && c3 < kk)          { sh_bin = 4u * ln + 2u; sh_above = c3; }
            if (c1 >= kk && c2 < kk)          { sh_bin = 4u * ln + 1u; sh_above = c2; }
            if (c0 >= kk && c1 < kk)          { sh_bin = 4u * ln + 0u; sh_above = c1; }
        }
        __syncthreads();
        kk -= sh_above;
        prefix |= (sh_bin << shift);
    }
    const float thr = __uint_as_float(prefix);

    // ---- sum of kept scores (2-barrier shfl reduction) ----
    float local = 0.f;
    for (int i = tid; i < NN; i += 1024) {
        float v = s[i];
        if (v >= thr) local += v;
    }
#pragma unroll
    for (int off = 32; off >= 1; off >>= 1) local += __shfl_down(local, off, 64);
    if ((tid & 63) == 0) wsum[tid >> 6] = local;
    __syncthreads();
    if (tid < 64) {
        float t = (tid < 16) ? wsum[tid] : 0.f;
#pragma unroll
        for (int off = 8; off >= 1; off >>= 1) t += __shfl_down(t, off, 64);
        if (tid == 0) wsum[0] = t;
    }
    __syncthreads();
    const float inv = 1.f / (wsum[0] + 1e-12f);

    // ---- weights/mask + compact list ----
    const int lane = tid & 63;
    for (int i = tid; i < NN; i += 1024) {
        float v = s[i];
        bool keep = (v >= thr);
        float m = keep ? 1.f : 0.f;
        weights[b * NN + i] = v * m * inv;
        mask[b * NN + i]    = m;
        if (kidx) {
            unsigned long long bal = __ballot(keep);
            int base = 0;
            if (lane == 0) base = atomicAdd(&scnt, __popcll(bal));
            base = __shfl(base, 0, 64);
            if (keep) {
                int off = __popcll(bal & ((1ULL << lane) - 1ULL));
                kidx[b * NN + base + off] = i;
                kw[b * NN + base + off]   = v * inv;
            }
        }
    }
    if (kidx) {
        __syncthreads();
        if (tid == 0) kcnt[b] = scnt;
    }
}

// ---------------- Kernel 3a: filtered_feat from compact list (float4 gather) ----------------
// ROUND-16: block covers 256 dims (grid 3 x 32 x NCH); per row a lane loads
// one float4 -> 4x fewer VMEM instructions for the same 201 MB of gather.
__global__ __launch_bounds__(256) void fapf_feat_compact(
    const float* __restrict__ x, const int* __restrict__ kidx,
    const float* __restrict__ kw, const int* __restrict__ kcnt,
    float* __restrict__ feat)
{
    const int b  = blockIdx.y;
    const int d0 = blockIdx.x * 256;
    const int ch = blockIdx.z;
    const int dl = threadIdx.x & 63;
    const int ng = threadIdx.x >> 6;   // 0..3 (wave id)

    const int cnt = kcnt[b];
    int per = (cnt + NCH - 1) / NCH;
    int j0 = ch * per; if (j0 > cnt) j0 = cnt;
    int j1 = j0 + per; if (j1 > cnt) j1 = cnt;
    int len = j1 - j0;
    int per_w = (len + 3) >> 2;
    int s = j0 + ng * per_w;
    int e = s + per_w; if (e > j1) e = j1;

    const float* xb  = x + (size_t)b * NN * DD + d0 + dl * 4;
    const int*   ib  = kidx + b * NN;
    const float* wbp = kw + b * NN;

    float4 a[8];
#pragma unroll
    for (int u = 0; u < 8; u++) a[u] = (float4){0.f, 0.f, 0.f, 0.f};

    int j = s;
    for (; j + 8 <= e; j += 8) {
        int   idx[8];
        float ww[8];
#pragma unroll
        for (int u = 0; u < 8; u++) { idx[u] = ib[j + u]; ww[u] = wbp[j + u]; }
        float4 v[8];
#pragma unroll
        for (int u = 0; u < 8; u++)
            v[u] = *(const float4*)&xb[(size_t)idx[u] * DD];
#pragma unroll
        for (int u = 0; u < 8; u++) {
            a[u].x = fmaf(ww[u], v[u].x, a[u].x);
            a[u].y = fmaf(ww[u], v[u].y, a[u].y);
            a[u].z = fmaf(ww[u], v[u].z, a[u].z);
            a[u].w = fmaf(ww[u], v[u].w, a[u].w);
        }
    }
    for (; j < e; j++) {
        float w = wbp[j];
        float4 v = *(const float4*)&xb[(size_t)ib[j] * DD];
        a[0].x = fmaf(w, v.x, a[0].x);
        a[0].y = fmaf(w, v.y, a[0].y);
        a[0].z = fmaf(w, v.z, a[0].z);
        a[0].w = fmaf(w, v.w, a[0].w);
    }

    float4 acc;
    acc.x = ((a[0].x + a[1].x) + (a[2].x + a[3].x)) + ((a[4].x + a[5].x) + (a[6].x + a[7].x));
    acc.y = ((a[0].y + a[1].y) + (a[2].y + a[3].y)) + ((a[4].y + a[5].y) + (a[6].y + a[7].y));
    acc.z = ((a[0].z + a[1].z) + (a[2].z + a[3].z)) + ((a[4].z + a[5].z) + (a[6].z + a[7].z));
    acc.w = ((a[0].w + a[1].w) + (a[2].w + a[3].w)) + ((a[4].w + a[5].w) + (a[6].w + a[7].w));

    __shared__ float4 red[4][64];
    red[ng][dl] = acc;
    __syncthreads();
    if (threadIdx.x < 64) {
        float4 r0 = red[0][dl], r1 = red[1][dl], r2 = red[2][dl], r3 = red[3][dl];
        float* fp = &feat[b * DD + d0 + dl * 4];
        atomicAdd(&fp[0], (r0.x + r1.x) + (r2.x + r3.x));
        atomicAdd(&fp[1], (r0.y + r1.y) + (r2.y + r3.y));
        atomicAdd(&fp[2], (r0.z + r1.z) + (r2.z + r3.z));
        atomicAdd(&fp[3], (r0.w + r1.w) + (r2.w + r3.w));
    }
}

// ---------------- Kernel 3b: dense fallback ----------------
__global__ __launch_bounds__(256) void fapf_feat_dense(
    const float* __restrict__ x, const float* __restrict__ weights,
    float* __restrict__ feat)
{
    const int b  = blockIdx.y;
    const int d0 = blockIdx.x * 64;
    const int dl = threadIdx.x & 63;
    const int ng = threadIdx.x >> 6;   // 0..3

    const float* xb = x + (size_t)b * NN * DD;
    const float* wb = weights + b * NN;

    float a0 = 0.f, a1 = 0.f, a2 = 0.f, a3 = 0.f;
    for (int n = ng; n < NN; n += 16) {
        float w0 = wb[n], w1v = wb[n + 4], w2v = wb[n + 8], w3 = wb[n + 12];
        float v0 = xb[(size_t)(n)      * DD + d0 + dl];
        float v1 = xb[(size_t)(n + 4)  * DD + d0 + dl];
        float v2 = xb[(size_t)(n + 8)  * DD + d0 + dl];
        float v3 = xb[(size_t)(n + 12) * DD + d0 + dl];
        a0 = fmaf(w0, v0, a0);
        a1 = fmaf(w1v, v1, a1);
        a2 = fmaf(w2v, v2, a2);
        a3 = fmaf(w3, v3, a3);
    }
    float acc = (a0 + a1) + (a2 + a3);

    __shared__ float red[4][64];
    red[ng][dl] = acc;
    __syncthreads();
    if (threadIdx.x < 64) {
        feat[b * DD + d0 + dl] =
            (red[0][dl] + red[1][dl]) + (red[2][dl] + red[3][dl]);
    }
}

extern "C" void kernel_launch(void* const* d_in, const int* in_sizes, int n_in,
                              void* d_out, int out_size, void* d_ws, size_t ws_size,
                              hipStream_t stream) {
    const float* x   = (const float*)d_in[0];
    const float* w1  = (const float*)d_in[1];
    const float* b1  = (const float*)d_in[2];
    const float* w2  = (const float*)d_in[3];
    const float* b2  = (const float*)d_in[4];
    const int*   pct = (const int*)d_in[5];

    float* out = (float*)d_out;
    float* feat    = out;                         // [32,768]
    float* weights = out + BB * DD;               // [32,4096]
    float* scores  = weights + BB * NN;           // [32,4096]
    float* mask    = scores + BB * NN;            // [32,4096]

    // d_ws layout: whf (576KB) | wlf (576KB) | kidx (512KB) | kw (512KB) | kcnt (128B)
    short* whf  = (short*)d_ws;
    short* wlf  = whf + 24 * 24 * 64 * 8;
    int*   kidx = (int*)(wlf + 24 * 24 * 64 * 8);
    float* kw   = (float*)(kidx + BB * NN);
    int*   kcnt = (int*)(kw + BB * NN);

    const size_t needed = 2 * (size_t)(24 * 24 * 64 * 8) * sizeof(short)
                        + (size_t)BB * NN * (sizeof(int) + sizeof(float))
                        + BB * sizeof(int);
    const bool compact = ws_size >= needed;

    fapf_prep_w<<<dim3(24, 24), dim3(64), 0, stream>>>(w1, whf, wlf);
    fapf_scores_mfma<<<dim3(BB * NN / 32), dim3(256), 0, stream>>>(
        x, whf, wlf, b1, w2, b2, scores);
    fapf_select_kernel<<<dim3(BB), dim3(1024), 0, stream>>>(
        scores, pct, weights, mask, feat,
        compact ? kidx : (int*)nullptr, kw, kcnt);
    if (compact) {
        fapf_feat_compact<<<dim3(DD / 256, BB, NCH), dim3(256), 0, stream>>>(
            x, kidx, kw, kcnt, feat);
    } else {
        fapf_feat_dense<<<dim3(DD / 64, BB), dim3(256), 0, stream>>>(
            x, weights, feat);
    }
}